// Round 1
// baseline (515.031 us; speedup 1.0000x reference)
//
#include <hip/hip_runtime.h>

#define B_ 4
#define C_ 64
#define IC_ 32
#define N_ 4096
#define LOG2E 1.44269504088896341f

typedef __attribute__((ext_vector_type(8))) short short8;
typedef __attribute__((ext_vector_type(4))) float floatx4;

__device__ __forceinline__ unsigned short f2bf(float f) {
  unsigned u = __float_as_uint(f);
  u += 0x7FFFu + ((u >> 16) & 1u);   // round-to-nearest-even
  return (unsigned short)(u >> 16);
}

// ---------------- conv 3x3 stride 2 pad 1, 64->64 ch, optional lrelu ----------------
template<int IN_H, int OUT_H, bool LRELU, int RP>
__global__ void __launch_bounds__(256) conv3x3s2_k(
    const float* __restrict__ in, const float* __restrict__ wt,
    const float* __restrict__ bias, float* __restrict__ out)
{
  constexpr int IN_SZ = IN_H * IN_H;
  constexpr int OUT_SZ = OUT_H * OUT_H;
  const int b  = blockIdx.x >> 6;
  const int oc = blockIdx.x & 63;
  __shared__ float s_in[IN_SZ];
  __shared__ float s_w[64 * 9];
  const int t = threadIdx.x;
  for (int i = t; i < 64 * 9; i += 256) s_w[i] = wt[oc * 576 + i];
  float acc[RP];
#pragma unroll
  for (int r = 0; r < RP; ++r) acc[r] = 0.f;
  const float* inb = in + (size_t)b * 64 * IN_SZ;
  for (int ic = 0; ic < 64; ++ic) {
    __syncthreads();
    for (int i = t; i < IN_SZ; i += 256) s_in[i] = inb[(size_t)ic * IN_SZ + i];
    __syncthreads();
    float wr[9];
#pragma unroll
    for (int k = 0; k < 9; ++k) wr[k] = s_w[ic * 9 + k];
#pragma unroll
    for (int r = 0; r < RP; ++r) {
      int o = t + r * 256;
      if (OUT_SZ >= 256 || o < OUT_SZ) {
        int oh = o / OUT_H, ow = o % OUT_H;
        int ih = oh * 2 - 1, iw = ow * 2 - 1;
        float s = 0.f;
#pragma unroll
        for (int kh = 0; kh < 3; ++kh) {
          int y = ih + kh;
          if ((unsigned)y < (unsigned)IN_H) {
#pragma unroll
            for (int kw = 0; kw < 3; ++kw) {
              int xx = iw + kw;
              if ((unsigned)xx < (unsigned)IN_H)
                s += s_in[y * IN_H + xx] * wr[kh * 3 + kw];
            }
          }
        }
        acc[r] += s;
      }
    }
  }
  float bv = bias[oc];
#pragma unroll
  for (int r = 0; r < RP; ++r) {
    int o = t + r * 256;
    if (OUT_SZ >= 256 || o < OUT_SZ) {
      float v = acc[r] + bv;
      if (LRELU) v = (v >= 0.f) ? v : 0.2f * v;
      out[((size_t)b * 64 + oc) * OUT_SZ + o] = v;
    }
  }
}

// ---------------- bilinear 8->64 upsample (half-pixel, edge clamp) + sigmoid gate ----------------
__global__ void __launch_bounds__(256) upsample_gate_k(
    const float* __restrict__ y3, const float* __restrict__ x, float* __restrict__ am)
{
  const int b = blockIdx.x >> 6, c = blockIdx.x & 63;
  __shared__ float s_y[64];
  const int t = threadIdx.x;
  if (t < 64) s_y[t] = y3[(size_t)(b * 64 + c) * 64 + t];
  __syncthreads();
  const float* xp = x  + (size_t)(b * 64 + c) * N_;
  float*       ap = am + (size_t)(b * 64 + c) * N_;
  for (int o = t; o < N_; o += 256) {
    int oh = o >> 6, ow = o & 63;
    float sh = (oh + 0.5f) * 0.125f - 0.5f;
    float sw = (ow + 0.5f) * 0.125f - 0.5f;
    float fh = floorf(sh), fw = floorf(sw);
    int h0 = (int)fh, w0 = (int)fw;
    float ah = sh - fh, aw = sw - fw;
    int h0c = min(7, max(0, h0)),     h1c = min(7, max(0, h0 + 1));
    int w0c = min(7, max(0, w0)),     w1c = min(7, max(0, w0 + 1));
    float v00 = s_y[h0c * 8 + w0c], v01 = s_y[h0c * 8 + w1c];
    float v10 = s_y[h1c * 8 + w0c], v11 = s_y[h1c * 8 + w1c];
    float v = (v00 * (1.f - aw) + v01 * aw) * (1.f - ah)
            + (v10 * (1.f - aw) + v11 * aw) * ah;
    float sig = 1.f / (1.f + __expf(-v));
    ap[o] = sig * xp[o];
  }
}

// ---------------- 1x1 projections theta/phi/g -> tpg f32 [B][96][N] ----------------
__global__ void __launch_bounds__(256) proj_k(
    const float* __restrict__ am,
    const float* __restrict__ th_w, const float* __restrict__ th_b,
    const float* __restrict__ ph_w, const float* __restrict__ ph_b,
    const float* __restrict__ g_w,  const float* __restrict__ g_b,
    float* __restrict__ tpg)
{
  const int n  = blockIdx.x * 256 + threadIdx.x;
  const int o0 = blockIdx.y * 8;           // 0..88
  const int b  = blockIdx.z;
  const float* wsrc; const float* bsrc;
  if (o0 < 32)      { wsrc = th_w + o0 * 64;        bsrc = th_b + o0; }
  else if (o0 < 64) { wsrc = ph_w + (o0 - 32) * 64; bsrc = ph_b + (o0 - 32); }
  else              { wsrc = g_w  + (o0 - 64) * 64; bsrc = g_b  + (o0 - 64); }
  const float* ap = am + (size_t)b * 64 * N_ + n;
  float acc[8];
#pragma unroll
  for (int u = 0; u < 8; ++u) acc[u] = bsrc[u];
  for (int c = 0; c < 64; ++c) {
    float a = ap[(size_t)c * N_];
#pragma unroll
    for (int u = 0; u < 8; ++u) acc[u] += wsrc[u * 64 + c] * a;
  }
  float* op = tpg + ((size_t)b * 96 + o0) * N_ + n;
#pragma unroll
  for (int u = 0; u < 8; ++u) op[(size_t)u * N_] = acc[u];
}

// ---------------- pack: tpg f32 -> thph bf16 channel-last [B][N][64] (theta*log2e) + g bf16 [B][32][N] ----------------
__global__ void __launch_bounds__(256) pack_k(
    const float* __restrict__ tpg,
    unsigned short* __restrict__ thph, unsigned short* __restrict__ g16)
{
  const int b  = blockIdx.y;
  const int n0 = blockIdx.x * 64;
  const int t  = threadIdx.x;
  __shared__ float s_t[64][65];
  for (int idx = t; idx < 4096; idx += 256) {
    int ch = idx >> 6, nn = idx & 63;
    float v = tpg[((size_t)b * 96 + ch) * N_ + n0 + nn];
    if (ch < 32) v *= LOG2E;
    s_t[ch][nn] = v;
  }
  for (int idx = t; idx < 2048; idx += 256) {
    int c = idx >> 6, nn = idx & 63;
    g16[((size_t)b * 32 + c) * N_ + n0 + nn] =
        f2bf(tpg[((size_t)b * 96 + 64 + c) * N_ + n0 + nn]);
  }
  __syncthreads();
  for (int idx = t; idx < 512; idx += 256) {
    int row = idx >> 3, ck = idx & 7;
    unsigned short u0 = f2bf(s_t[ck * 8 + 0][row]), u1 = f2bf(s_t[ck * 8 + 1][row]);
    unsigned short u2 = f2bf(s_t[ck * 8 + 2][row]), u3 = f2bf(s_t[ck * 8 + 3][row]);
    unsigned short u4 = f2bf(s_t[ck * 8 + 4][row]), u5 = f2bf(s_t[ck * 8 + 5][row]);
    unsigned short u6 = f2bf(s_t[ck * 8 + 6][row]), u7 = f2bf(s_t[ck * 8 + 7][row]);
    uint4 pkt;
    pkt.x = (unsigned)u0 | ((unsigned)u1 << 16);
    pkt.y = (unsigned)u2 | ((unsigned)u3 << 16);
    pkt.z = (unsigned)u4 | ((unsigned)u5 << 16);
    pkt.w = (unsigned)u6 | ((unsigned)u7 << 16);
    *reinterpret_cast<uint4*>(&thph[((size_t)b * N_ + n0 + row) * 64 + ck * 8]) = pkt;
  }
}

// ---------------- pass A: l_j = sum_i exp2(S'_ij), partial over i-quarter ----------------
// grid (N/128, B, 4); wave owns 32 j-columns (2 subtiles), loops its i-quarter.
__global__ void __launch_bounds__(256) attn_stats_k(
    const unsigned short* __restrict__ thph, float* __restrict__ lpart)
{
  const int b  = blockIdx.y;
  const int iz = blockIdx.z;
  const int j0 = blockIdx.x * 128;
  const int t = threadIdx.x, wave = t >> 6, lane = t & 63;
  const int n15 = lane & 15, quad = lane >> 4;
  const int jw = j0 + wave * 32;
  const unsigned short* base = thph + (size_t)b * N_ * 64;
  const short8 b0 = *reinterpret_cast<const short8*>(base + (size_t)(jw + n15) * 64 + 32 + quad * 8);
  const short8 b1 = *reinterpret_cast<const short8*>(base + (size_t)(jw + 16 + n15) * 64 + 32 + quad * 8);
  float ls0 = 0.f, ls1 = 0.f;
  const unsigned short* ab = base + (size_t)(iz * 1024 + n15) * 64 + quad * 8;
#pragma unroll 4
  for (int ii = 0; ii < 64; ++ii) {
    short8 a = *reinterpret_cast<const short8*>(ab + (size_t)ii * 1024);
    floatx4 z0 = {0.f, 0.f, 0.f, 0.f}, z1 = {0.f, 0.f, 0.f, 0.f};
    z0 = __builtin_amdgcn_mfma_f32_16x16x32_bf16(a, b0, z0, 0, 0, 0);
    z1 = __builtin_amdgcn_mfma_f32_16x16x32_bf16(a, b1, z1, 0, 0, 0);
    ls0 += exp2f(z0[0]) + exp2f(z0[1]) + exp2f(z0[2]) + exp2f(z0[3]);
    ls1 += exp2f(z1[0]) + exp2f(z1[1]) + exp2f(z1[2]) + exp2f(z1[3]);
  }
  ls0 += __shfl_xor(ls0, 16); ls0 += __shfl_xor(ls0, 32);
  ls1 += __shfl_xor(ls1, 16); ls1 += __shfl_xor(ls1, 32);
  if (quad == 0) {
    lpart[((size_t)iz * B_ + b) * N_ + jw + n15]      = ls0;
    lpart[((size_t)iz * B_ + b) * N_ + jw + 16 + n15] = ls1;
  }
}

// ---------------- pass B: Y[i][c] = sum_j exp2(S')/l_j * g[c][j] ----------------
// grid (N/64, B, 2); wave owns 16 i-rows, loops its j-half in 64-j chunks.
__global__ void __launch_bounds__(256) attn_pv_k(
    const unsigned short* __restrict__ thph, const unsigned short* __restrict__ g16,
    const float* __restrict__ lpart, float* __restrict__ y2p)
{
  const int b  = blockIdx.y;
  const int i0 = blockIdx.x * 64;
  const int jh = blockIdx.z;
  const int t = threadIdx.x, wave = t >> 6, lane = t & 63;
  const int n15 = lane & 15, quad = lane >> 4;
  const int iw = i0 + wave * 16;
  const unsigned short* base  = thph + (size_t)b * N_ * 64;
  const unsigned short* gbase = g16  + (size_t)b * 32 * N_;
  __shared__ float s_P[4][16][68];
  const short8 afrag = *reinterpret_cast<const short8*>(base + (size_t)(iw + n15) * 64 + quad * 8);
  floatx4 Y0 = {0.f, 0.f, 0.f, 0.f}, Y1 = {0.f, 0.f, 0.f, 0.f};
  for (int j0 = jh * 2048; j0 < jh * 2048 + 2048; j0 += 64) {
    float lv = lpart[(size_t)b * N_ + j0 + lane]
             + lpart[((size_t)1 * B_ + b) * N_ + j0 + lane]
             + lpart[((size_t)2 * B_ + b) * N_ + j0 + lane]
             + lpart[((size_t)3 * B_ + b) * N_ + j0 + lane];
    float rlv = 1.f / lv;
#pragma unroll
    for (int js = 0; js < 4; ++js) {
      short8 bfr = *reinterpret_cast<const short8*>(
          base + (size_t)(j0 + js * 16 + n15) * 64 + 32 + quad * 8);
      floatx4 z = {0.f, 0.f, 0.f, 0.f};
      z = __builtin_amdgcn_mfma_f32_16x16x32_bf16(afrag, bfr, z, 0, 0, 0);
      float r = __shfl(rlv, js * 16 + n15, 64);
#pragma unroll
      for (int reg = 0; reg < 4; ++reg)
        s_P[wave][quad * 4 + reg][js * 16 + n15] = exp2f(z[reg]) * r;
    }
    // per-wave LDS, same-wave RAW: compiler inserts lgkmcnt waits; no barrier needed
#pragma unroll
    for (int kc = 0; kc < 2; ++kc) {
      const float* pp = &s_P[wave][n15][kc * 32 + quad * 8];
      short8 pa;
#pragma unroll
      for (int e = 0; e < 8; ++e) pa[e] = (short)f2bf(pp[e]);
      short8 bg0 = *reinterpret_cast<const short8*>(
          gbase + (size_t)n15 * N_ + j0 + kc * 32 + quad * 8);
      short8 bg1 = *reinterpret_cast<const short8*>(
          gbase + (size_t)(16 + n15) * N_ + j0 + kc * 32 + quad * 8);
      Y0 = __builtin_amdgcn_mfma_f32_16x16x32_bf16(pa, bg0, Y0, 0, 0, 0);
      Y1 = __builtin_amdgcn_mfma_f32_16x16x32_bf16(pa, bg1, Y1, 0, 0, 0);
    }
  }
  // D layout: row(i) = quad*4+reg, col(c) = n15
#pragma unroll
  for (int reg = 0; reg < 4; ++reg) {
    y2p[(((size_t)jh * B_ + b) * 32 + n15)      * N_ + iw + quad * 4 + reg] = Y0[reg];
    y2p[(((size_t)jh * B_ + b) * 32 + 16 + n15) * N_ + iw + quad * 4 + reg] = Y1[reg];
  }
}

// ---------------- final: out = (W_y(y2) + am) * x ----------------
__global__ void __launch_bounds__(256) final_k(
    const float* __restrict__ y2p, const float* __restrict__ w_w,
    const float* __restrict__ w_b, const float* __restrict__ am,
    const float* __restrict__ x, float* __restrict__ out)
{
  const int n  = blockIdx.x * 256 + threadIdx.x;
  const int o0 = blockIdx.y * 8;
  const int b  = blockIdx.z;
  float acc[8];
#pragma unroll
  for (int u = 0; u < 8; ++u) acc[u] = w_b[o0 + u];
  const float* yp0 = y2p + (size_t)b * 32 * N_ + n;
  const float* yp1 = y2p + ((size_t)B_ + b) * 32 * N_ + n;
  for (int c = 0; c < 32; ++c) {
    float v = yp0[(size_t)c * N_] + yp1[(size_t)c * N_];
#pragma unroll
    for (int u = 0; u < 8; ++u) acc[u] += w_w[(o0 + u) * 32 + c] * v;
  }
#pragma unroll
  for (int u = 0; u < 8; ++u) {
    size_t off = ((size_t)b * 64 + o0 + u) * N_ + n;
    out[off] = (acc[u] + am[off]) * x[off];
  }
}

extern "C" void kernel_launch(void* const* d_in, const int* in_sizes, int n_in,
                              void* d_out, int out_size, void* d_ws, size_t ws_size,
                              hipStream_t stream) {
  const float* x    = (const float*)d_in[0];
  const float* d1_w = (const float*)d_in[1];
  const float* d1_b = (const float*)d_in[2];
  const float* d2_w = (const float*)d_in[3];
  const float* d2_b = (const float*)d_in[4];
  const float* d3_w = (const float*)d_in[5];
  const float* d3_b = (const float*)d_in[6];
  const float* g_w  = (const float*)d_in[7];
  const float* g_b  = (const float*)d_in[8];
  const float* th_w = (const float*)d_in[9];
  const float* th_b = (const float*)d_in[10];
  const float* ph_w = (const float*)d_in[11];
  const float* ph_b = (const float*)d_in[12];
  const float* w_w  = (const float*)d_in[13];
  const float* w_b  = (const float*)d_in[14];
  float* out = (float*)d_out;

  // workspace carve (floats). tpg f32 region is reused: conv temps live in its
  // tail (dead once proj runs), y2p overlays its head (tpg dead once pack runs).
  float* ws    = (float*)d_ws;
  float* am    = ws;                                   // [B][64][N]   1,048,576 f
  float* tpg   = am  + (size_t)B_ * 64 * N_;           // [B][96][N]   1,572,864 f
  float* lpart = tpg + (size_t)B_ * 96 * N_;           // [4][B][N]       65,536 f
  unsigned short* thph = (unsigned short*)(lpart + (size_t)4 * B_ * N_); // [B][N][64] bf16
  unsigned short* g16  = thph + (size_t)B_ * N_ * 64;                     // [B][32][N] bf16
  float* y2p = tpg;                                    // [2][B][32][N] 1,048,576 f (alias)
  float* y1  = tpg + (size_t)2 * B_ * 32 * N_;         // conv temps alias tpg tail
  float* yc2 = y1  + 262144;
  float* yc3 = yc2 + 65536;

  conv3x3s2_k<64, 32, true, 4><<<256, 256, 0, stream>>>(x,   d1_w, d1_b, y1);
  conv3x3s2_k<32, 16, true, 1><<<256, 256, 0, stream>>>(y1,  d2_w, d2_b, yc2);
  conv3x3s2_k<16,  8, false,1><<<256, 256, 0, stream>>>(yc2, d3_w, d3_b, yc3);
  upsample_gate_k<<<256, 256, 0, stream>>>(yc3, x, am);
  proj_k<<<dim3(16, 12, 4), 256, 0, stream>>>(am, th_w, th_b, ph_w, ph_b, g_w, g_b, tpg);
  pack_k<<<dim3(64, 4), 256, 0, stream>>>(tpg, thph, g16);
  attn_stats_k<<<dim3(32, 4, 4), 256, 0, stream>>>(thph, lpart);
  attn_pv_k<<<dim3(64, 4, 2), 256, 0, stream>>>(thph, g16, lpart, y2p);
  final_k<<<dim3(16, 8, 4), 256, 0, stream>>>(y2p, w_w, w_b, am, x, out);
}

// Round 2
// 431.337 us; speedup vs baseline: 1.1940x; 1.1940x over previous
//
#include <hip/hip_runtime.h>

#define B_ 4
#define C_ 64
#define IC_ 32
#define N_ 4096
#define LOG2E 1.44269504088896341f

typedef __attribute__((ext_vector_type(8))) short short8;
typedef __attribute__((ext_vector_type(4))) float floatx4;

__device__ __forceinline__ unsigned short f2bf(float f) {
  unsigned u = __float_as_uint(f);
  u += 0x7FFFu + ((u >> 16) & 1u);   // round-to-nearest-even
  return (unsigned short)(u >> 16);
}

// ---------------- direct conv 3x3 stride 2 pad 1, 64->64 ch, optional lrelu ----------
// Thread-per-output, NO inner barriers, no input LDS. Weights are wave-uniform
// (oc uniform per wave) -> compiler scalarizes to s_load. Input taps hit L1/L2.
// grid.x = B * (64/OCPB) * SPLIT, 256 threads.
template<int IN_H, int OUT_H, bool LRELU, int OCPB, int SPLIT>
__global__ void __launch_bounds__(256) convd_k(
    const float* __restrict__ in, const float* __restrict__ wt,
    const float* __restrict__ bias, float* __restrict__ out)
{
  constexpr int IN_SZ = IN_H * IN_H;
  constexpr int OUT_SZ = OUT_H * OUT_H;
  constexpr int PER_OC = OUT_SZ / SPLIT;     // outputs per oc per block
  const int t = threadIdx.x;
  int bx = blockIdx.x;
  const int seg = bx % SPLIT; bx /= SPLIT;
  const int ocg = bx % (64 / OCPB);
  const int b   = bx / (64 / OCPB);
  const int oc  = ocg * OCPB + t / PER_OC;   // wave-uniform (PER_OC multiple of 64)
  const int o   = seg * PER_OC + t % PER_OC;
  const int oh = o / OUT_H, ow = o % OUT_H;
  const int ih = oh * 2 - 1, iw = ow * 2 - 1;
  const float* __restrict__ inb = in + (size_t)b * 64 * IN_SZ;
  const float* __restrict__ wp  = wt + (size_t)oc * 576;
  float acc = 0.f;
#pragma unroll 2
  for (int ic = 0; ic < 64; ++ic) {
    const float* icp = inb + (size_t)ic * IN_SZ;
    const float* wr  = wp + ic * 9;
#pragma unroll
    for (int kh = 0; kh < 3; ++kh) {
      int y = ih + kh;
      if ((unsigned)y < (unsigned)IN_H) {
#pragma unroll
        for (int kw = 0; kw < 3; ++kw) {
          int xx = iw + kw;
          if ((unsigned)xx < (unsigned)IN_H)
            acc += icp[y * IN_H + xx] * wr[kh * 3 + kw];
        }
      }
    }
  }
  float v = acc + bias[oc];
  if (LRELU) v = (v >= 0.f) ? v : 0.2f * v;
  out[((size_t)b * 64 + oc) * OUT_SZ + o] = v;
}

// ---------------- bilinear 8->64 upsample (half-pixel, edge clamp) + sigmoid gate ----------------
__global__ void __launch_bounds__(256) upsample_gate_k(
    const float* __restrict__ y3, const float* __restrict__ x, float* __restrict__ am)
{
  const int b = blockIdx.x >> 6, c = blockIdx.x & 63;
  __shared__ float s_y[64];
  const int t = threadIdx.x;
  if (t < 64) s_y[t] = y3[(size_t)(b * 64 + c) * 64 + t];
  __syncthreads();
  const float* xp = x  + (size_t)(b * 64 + c) * N_;
  float*       ap = am + (size_t)(b * 64 + c) * N_;
  for (int o = t; o < N_; o += 256) {
    int oh = o >> 6, ow = o & 63;
    float sh = (oh + 0.5f) * 0.125f - 0.5f;
    float sw = (ow + 0.5f) * 0.125f - 0.5f;
    float fh = floorf(sh), fw = floorf(sw);
    int h0 = (int)fh, w0 = (int)fw;
    float ah = sh - fh, aw = sw - fw;
    int h0c = min(7, max(0, h0)),     h1c = min(7, max(0, h0 + 1));
    int w0c = min(7, max(0, w0)),     w1c = min(7, max(0, w0 + 1));
    float v00 = s_y[h0c * 8 + w0c], v01 = s_y[h0c * 8 + w1c];
    float v10 = s_y[h1c * 8 + w0c], v11 = s_y[h1c * 8 + w1c];
    float v = (v00 * (1.f - aw) + v01 * aw) * (1.f - ah)
            + (v10 * (1.f - aw) + v11 * aw) * ah;
    float sig = 1.f / (1.f + __expf(-v));
    ap[o] = sig * xp[o];
  }
}

// ---------------- 1x1 projections theta/phi/g -> tpg f32 [B][96][N] ----------------
__global__ void __launch_bounds__(256) proj_k(
    const float* __restrict__ am,
    const float* __restrict__ th_w, const float* __restrict__ th_b,
    const float* __restrict__ ph_w, const float* __restrict__ ph_b,
    const float* __restrict__ g_w,  const float* __restrict__ g_b,
    float* __restrict__ tpg)
{
  const int n  = blockIdx.x * 256 + threadIdx.x;
  const int o0 = blockIdx.y * 8;           // 0..88
  const int b  = blockIdx.z;
  const float* wsrc; const float* bsrc;
  if (o0 < 32)      { wsrc = th_w + o0 * 64;        bsrc = th_b + o0; }
  else if (o0 < 64) { wsrc = ph_w + (o0 - 32) * 64; bsrc = ph_b + (o0 - 32); }
  else              { wsrc = g_w  + (o0 - 64) * 64; bsrc = g_b  + (o0 - 64); }
  const float* ap = am + (size_t)b * 64 * N_ + n;
  float acc[8];
#pragma unroll
  for (int u = 0; u < 8; ++u) acc[u] = bsrc[u];
  for (int c = 0; c < 64; ++c) {
    float a = ap[(size_t)c * N_];
#pragma unroll
    for (int u = 0; u < 8; ++u) acc[u] += wsrc[u * 64 + c] * a;
  }
  float* op = tpg + ((size_t)b * 96 + o0) * N_ + n;
#pragma unroll
  for (int u = 0; u < 8; ++u) op[(size_t)u * N_] = acc[u];
}

// ---------------- pack: tpg f32 -> thph bf16 channel-last [B][N][64] (theta*log2e) + g bf16 [B][32][N] ----------------
__global__ void __launch_bounds__(256) pack_k(
    const float* __restrict__ tpg,
    unsigned short* __restrict__ thph, unsigned short* __restrict__ g16)
{
  const int b  = blockIdx.y;
  const int n0 = blockIdx.x * 64;
  const int t  = threadIdx.x;
  __shared__ float s_t[64][65];
  for (int idx = t; idx < 4096; idx += 256) {
    int ch = idx >> 6, nn = idx & 63;
    float v = tpg[((size_t)b * 96 + ch) * N_ + n0 + nn];
    if (ch < 32) v *= LOG2E;
    s_t[ch][nn] = v;
  }
  for (int idx = t; idx < 2048; idx += 256) {
    int c = idx >> 6, nn = idx & 63;
    g16[((size_t)b * 32 + c) * N_ + n0 + nn] =
        f2bf(tpg[((size_t)b * 96 + 64 + c) * N_ + n0 + nn]);
  }
  __syncthreads();
  for (int idx = t; idx < 512; idx += 256) {
    int row = idx >> 3, ck = idx & 7;
    unsigned short u0 = f2bf(s_t[ck * 8 + 0][row]), u1 = f2bf(s_t[ck * 8 + 1][row]);
    unsigned short u2 = f2bf(s_t[ck * 8 + 2][row]), u3 = f2bf(s_t[ck * 8 + 3][row]);
    unsigned short u4 = f2bf(s_t[ck * 8 + 4][row]), u5 = f2bf(s_t[ck * 8 + 5][row]);
    unsigned short u6 = f2bf(s_t[ck * 8 + 6][row]), u7 = f2bf(s_t[ck * 8 + 7][row]);
    uint4 pkt;
    pkt.x = (unsigned)u0 | ((unsigned)u1 << 16);
    pkt.y = (unsigned)u2 | ((unsigned)u3 << 16);
    pkt.z = (unsigned)u4 | ((unsigned)u5 << 16);
    pkt.w = (unsigned)u6 | ((unsigned)u7 << 16);
    *reinterpret_cast<uint4*>(&thph[((size_t)b * N_ + n0 + row) * 64 + ck * 8]) = pkt;
  }
}

// ---------------- pass A: l_j = sum_i exp2(S'_ij), partial over i-quarter ----------------
__global__ void __launch_bounds__(256) attn_stats_k(
    const unsigned short* __restrict__ thph, float* __restrict__ lpart)
{
  const int b  = blockIdx.y;
  const int iz = blockIdx.z;
  const int j0 = blockIdx.x * 128;
  const int t = threadIdx.x, wave = t >> 6, lane = t & 63;
  const int n15 = lane & 15, quad = lane >> 4;
  const int jw = j0 + wave * 32;
  const unsigned short* base = thph + (size_t)b * N_ * 64;
  const short8 b0 = *reinterpret_cast<const short8*>(base + (size_t)(jw + n15) * 64 + 32 + quad * 8);
  const short8 b1 = *reinterpret_cast<const short8*>(base + (size_t)(jw + 16 + n15) * 64 + 32 + quad * 8);
  float ls0 = 0.f, ls1 = 0.f;
  const unsigned short* ab = base + (size_t)(iz * 1024 + n15) * 64 + quad * 8;
#pragma unroll 4
  for (int ii = 0; ii < 64; ++ii) {
    short8 a = *reinterpret_cast<const short8*>(ab + (size_t)ii * 1024);
    floatx4 z0 = {0.f, 0.f, 0.f, 0.f}, z1 = {0.f, 0.f, 0.f, 0.f};
    z0 = __builtin_amdgcn_mfma_f32_16x16x32_bf16(a, b0, z0, 0, 0, 0);
    z1 = __builtin_amdgcn_mfma_f32_16x16x32_bf16(a, b1, z1, 0, 0, 0);
    ls0 += exp2f(z0[0]) + exp2f(z0[1]) + exp2f(z0[2]) + exp2f(z0[3]);
    ls1 += exp2f(z1[0]) + exp2f(z1[1]) + exp2f(z1[2]) + exp2f(z1[3]);
  }
  ls0 += __shfl_xor(ls0, 16); ls0 += __shfl_xor(ls0, 32);
  ls1 += __shfl_xor(ls1, 16); ls1 += __shfl_xor(ls1, 32);
  if (quad == 0) {
    lpart[((size_t)iz * B_ + b) * N_ + jw + n15]      = ls0;
    lpart[((size_t)iz * B_ + b) * N_ + jw + 16 + n15] = ls1;
  }
}

// ---------------- pass B: Y[i][c] = sum_j exp2(S')/l_j * g[c][j] ----------------
__global__ void __launch_bounds__(256) attn_pv_k(
    const unsigned short* __restrict__ thph, const unsigned short* __restrict__ g16,
    const float* __restrict__ lpart, float* __restrict__ y2p)
{
  const int b  = blockIdx.y;
  const int i0 = blockIdx.x * 64;
  const int jh = blockIdx.z;
  const int t = threadIdx.x, wave = t >> 6, lane = t & 63;
  const int n15 = lane & 15, quad = lane >> 4;
  const int iw = i0 + wave * 16;
  const unsigned short* base  = thph + (size_t)b * N_ * 64;
  const unsigned short* gbase = g16  + (size_t)b * 32 * N_;
  __shared__ float s_P[4][16][68];
  const short8 afrag = *reinterpret_cast<const short8*>(base + (size_t)(iw + n15) * 64 + quad * 8);
  floatx4 Y0 = {0.f, 0.f, 0.f, 0.f}, Y1 = {0.f, 0.f, 0.f, 0.f};
  for (int j0 = jh * 2048; j0 < jh * 2048 + 2048; j0 += 64) {
    float lv = lpart[(size_t)b * N_ + j0 + lane]
             + lpart[((size_t)1 * B_ + b) * N_ + j0 + lane]
             + lpart[((size_t)2 * B_ + b) * N_ + j0 + lane]
             + lpart[((size_t)3 * B_ + b) * N_ + j0 + lane];
    float rlv = 1.f / lv;
#pragma unroll
    for (int js = 0; js < 4; ++js) {
      short8 bfr = *reinterpret_cast<const short8*>(
          base + (size_t)(j0 + js * 16 + n15) * 64 + 32 + quad * 8);
      floatx4 z = {0.f, 0.f, 0.f, 0.f};
      z = __builtin_amdgcn_mfma_f32_16x16x32_bf16(afrag, bfr, z, 0, 0, 0);
      float r = __shfl(rlv, js * 16 + n15, 64);
#pragma unroll
      for (int reg = 0; reg < 4; ++reg)
        s_P[wave][quad * 4 + reg][js * 16 + n15] = exp2f(z[reg]) * r;
    }
#pragma unroll
    for (int kc = 0; kc < 2; ++kc) {
      const float* pp = &s_P[wave][n15][kc * 32 + quad * 8];
      short8 pa;
#pragma unroll
      for (int e = 0; e < 8; ++e) pa[e] = (short)f2bf(pp[e]);
      short8 bg0 = *reinterpret_cast<const short8*>(
          gbase + (size_t)n15 * N_ + j0 + kc * 32 + quad * 8);
      short8 bg1 = *reinterpret_cast<const short8*>(
          gbase + (size_t)(16 + n15) * N_ + j0 + kc * 32 + quad * 8);
      Y0 = __builtin_amdgcn_mfma_f32_16x16x32_bf16(pa, bg0, Y0, 0, 0, 0);
      Y1 = __builtin_amdgcn_mfma_f32_16x16x32_bf16(pa, bg1, Y1, 0, 0, 0);
    }
  }
#pragma unroll
  for (int reg = 0; reg < 4; ++reg) {
    y2p[(((size_t)jh * B_ + b) * 32 + n15)      * N_ + iw + quad * 4 + reg] = Y0[reg];
    y2p[(((size_t)jh * B_ + b) * 32 + 16 + n15) * N_ + iw + quad * 4 + reg] = Y1[reg];
  }
}

// ---------------- final: out = (W_y(y2) + am) * x ----------------
__global__ void __launch_bounds__(256) final_k(
    const float* __restrict__ y2p, const float* __restrict__ w_w,
    const float* __restrict__ w_b, const float* __restrict__ am,
    const float* __restrict__ x, float* __restrict__ out)
{
  const int n  = blockIdx.x * 256 + threadIdx.x;
  const int o0 = blockIdx.y * 8;
  const int b  = blockIdx.z;
  float acc[8];
#pragma unroll
  for (int u = 0; u < 8; ++u) acc[u] = w_b[o0 + u];
  const float* yp0 = y2p + (size_t)b * 32 * N_ + n;
  const float* yp1 = y2p + ((size_t)B_ + b) * 32 * N_ + n;
  for (int c = 0; c < 32; ++c) {
    float v = yp0[(size_t)c * N_] + yp1[(size_t)c * N_];
#pragma unroll
    for (int u = 0; u < 8; ++u) acc[u] += w_w[(o0 + u) * 32 + c] * v;
  }
#pragma unroll
  for (int u = 0; u < 8; ++u) {
    size_t off = ((size_t)b * 64 + o0 + u) * N_ + n;
    out[off] = (acc[u] + am[off]) * x[off];
  }
}

extern "C" void kernel_launch(void* const* d_in, const int* in_sizes, int n_in,
                              void* d_out, int out_size, void* d_ws, size_t ws_size,
                              hipStream_t stream) {
  const float* x    = (const float*)d_in[0];
  const float* d1_w = (const float*)d_in[1];
  const float* d1_b = (const float*)d_in[2];
  const float* d2_w = (const float*)d_in[3];
  const float* d2_b = (const float*)d_in[4];
  const float* d3_w = (const float*)d_in[5];
  const float* d3_b = (const float*)d_in[6];
  const float* g_w  = (const float*)d_in[7];
  const float* g_b  = (const float*)d_in[8];
  const float* th_w = (const float*)d_in[9];
  const float* th_b = (const float*)d_in[10];
  const float* ph_w = (const float*)d_in[11];
  const float* ph_b = (const float*)d_in[12];
  const float* w_w  = (const float*)d_in[13];
  const float* w_b  = (const float*)d_in[14];
  float* out = (float*)d_out;

  float* ws    = (float*)d_ws;
  float* am    = ws;                                   // [B][64][N]
  float* tpg   = am  + (size_t)B_ * 64 * N_;           // [B][96][N]
  float* lpart = tpg + (size_t)B_ * 96 * N_;           // [4][B][N]
  unsigned short* thph = (unsigned short*)(lpart + (size_t)4 * B_ * N_); // [B][N][64] bf16
  unsigned short* g16  = thph + (size_t)B_ * N_ * 64;                     // [B][32][N] bf16
  float* y2p = tpg;                                    // [2][B][32][N] (alias)
  float* y1  = tpg + (size_t)2 * B_ * 32 * N_;         // conv temps alias tpg tail
  float* yc2 = y1  + 262144;
  float* yc3 = yc2 + 65536;

  convd_k<64, 32, true,  1, 4><<<1024, 256, 0, stream>>>(x,   d1_w, d1_b, y1);
  convd_k<32, 16, true,  1, 1><<<256,  256, 0, stream>>>(y1,  d2_w, d2_b, yc2);
  convd_k<16,  8, false, 4, 1><<<64,   256, 0, stream>>>(yc2, d3_w, d3_b, yc3);
  upsample_gate_k<<<256, 256, 0, stream>>>(yc3, x, am);
  proj_k<<<dim3(16, 12, 4), 256, 0, stream>>>(am, th_w, th_b, ph_w, ph_b, g_w, g_b, tpg);
  pack_k<<<dim3(64, 4), 256, 0, stream>>>(tpg, thph, g16);
  attn_stats_k<<<dim3(32, 4, 4), 256, 0, stream>>>(thph, lpart);
  attn_pv_k<<<dim3(64, 4, 2), 256, 0, stream>>>(thph, g16, lpart, y2p);
  final_k<<<dim3(16, 8, 4), 256, 0, stream>>>(y2p, w_w, w_b, am, x, out);
}

// Round 3
// 219.068 us; speedup vs baseline: 2.3510x; 1.9690x over previous
//
#include <hip/hip_runtime.h>

#define B_ 4
#define C_ 64
#define IC_ 32
#define N_ 4096
#define LOG2E 1.44269504088896341f

typedef __attribute__((ext_vector_type(8))) short short8;
typedef __attribute__((ext_vector_type(4))) float floatx4;

__device__ __forceinline__ unsigned short f2bf(float f) {
  unsigned u = __float_as_uint(f);
  u += 0x7FFFu + ((u >> 16) & 1u);   // round-to-nearest-even
  return (unsigned short)(u >> 16);
}
__device__ __forceinline__ float bf2f(unsigned short h) {
  return __uint_as_float(((unsigned)h) << 16);
}

// ---------------- weight pack: convs -> [tap][oc][ic] bf16; proj -> [96][64] bf16 ----------------
__global__ void __launch_bounds__(256) pack_w_k(
    const float* __restrict__ d1_w, const float* __restrict__ d2_w, const float* __restrict__ d3_w,
    const float* __restrict__ th_w, const float* __restrict__ ph_w, const float* __restrict__ g_w,
    const float* __restrict__ th_b, const float* __restrict__ ph_b, const float* __restrict__ g_b,
    unsigned short* __restrict__ wpk, unsigned short* __restrict__ wproj, float* __restrict__ bproj)
{
  const int tid = blockIdx.x * 256 + threadIdx.x;
  for (int idx = tid; idx < 3 * 36864; idx += gridDim.x * 256) {
    int cv = idx / 36864, r = idx % 36864;
    int tap = r / 4096, r2 = r % 4096;
    int oc = r2 >> 6, ic = r2 & 63;
    const float* src = (cv == 0) ? d1_w : (cv == 1) ? d2_w : d3_w;
    wpk[(size_t)cv * 36864 + tap * 4096 + oc * 64 + ic] = f2bf(src[oc * 576 + ic * 9 + tap]);
  }
  for (int idx = tid; idx < 6144; idx += gridDim.x * 256) {
    int m = idx >> 6, ic = idx & 63;
    float v = (m < 32) ? LOG2E * th_w[m * 64 + ic]
            : (m < 64) ? ph_w[(m - 32) * 64 + ic]
                       : g_w[(m - 64) * 64 + ic];
    wproj[m * 64 + ic] = f2bf(v);
  }
  for (int m = tid; m < 96; m += gridDim.x * 256) {
    bproj[m] = (m < 32) ? LOG2E * th_b[m] : (m < 64) ? ph_b[m - 32] : g_b[m - 64];
  }
}

// ---------------- pack x: [b][64c][64h][64w] f32 -> padded channel-last bf16 [b][66][66][64] ----------------
__global__ void __launch_bounds__(256) pack_x_k(
    const float* __restrict__ x, unsigned short* __restrict__ xclp)
{
  const int b = blockIdx.x >> 6, h = blockIdx.x & 63;
  const int t = threadIdx.x;
  __shared__ float s[64][65];
  for (int idx = t; idx < 4096; idx += 256) {
    int c = idx >> 6, w = idx & 63;
    s[c][w] = x[((size_t)(b * 64 + c)) * 4096 + h * 64 + w];
  }
  __syncthreads();
  for (int idx = t; idx < 4096; idx += 256) {
    int w = idx >> 6, c = idx & 63;
    xclp[(((size_t)b * 66 + h + 1) * 66 + (w + 1)) * 64 + c] = f2bf(s[c][w]);
  }
}

// ---------------- implicit-GEMM conv 3x3 s2, 64->64 ch, MFMA bf16 ----------------
// Input: padded channel-last bf16 [b][IN_PW][IN_PW][64]. Output: padded cl bf16 (+lrelu)
// or flat [b][OUT_H*OUT_H][64] f32. Block = 4 waves = 4 oc-tiles, one 16-output tile.
template<int IN_PW, int OUT_H, bool LRELU, bool OUT_BF16>
__global__ void __launch_bounds__(256) convmf_k(
    const unsigned short* __restrict__ xin, const unsigned short* __restrict__ wp,
    const float* __restrict__ bias, unsigned short* __restrict__ obf,
    float* __restrict__ of32)
{
  constexpr int NTILES = OUT_H * OUT_H / 16;
  const int t = threadIdx.x, wave = t >> 6, lane = t & 63;
  const int n15 = lane & 15, quad = lane >> 4;
  const int otile = blockIdx.x % NTILES;
  const int b = blockIdx.x / NTILES;
  const int o = otile * 16 + n15;
  const int oh = o / OUT_H, ow = o % OUT_H;
  const unsigned short* xb = xin + (size_t)b * IN_PW * IN_PW * 64;
  floatx4 acc = {0.f, 0.f, 0.f, 0.f};
#pragma unroll
  for (int tap = 0; tap < 9; ++tap) {
    const int kh = tap / 3, kw = tap % 3;
    const unsigned short* xpix = xb + ((size_t)(oh * 2 + kh) * IN_PW + (ow * 2 + kw)) * 64;
#pragma unroll
    for (int ks = 0; ks < 2; ++ks) {
      short8 af = *reinterpret_cast<const short8*>(
          wp + ((size_t)tap * 64 + wave * 16 + n15) * 64 + ks * 32 + quad * 8);
      short8 bf = *reinterpret_cast<const short8*>(xpix + ks * 32 + quad * 8);
      acc = __builtin_amdgcn_mfma_f32_16x16x32_bf16(af, bf, acc, 0, 0, 0);
    }
  }
  const float4 bv = *reinterpret_cast<const float4*>(bias + wave * 16 + quad * 4);
  float v[4] = {acc[0] + bv.x, acc[1] + bv.y, acc[2] + bv.z, acc[3] + bv.w};
  if (LRELU) {
#pragma unroll
    for (int r = 0; r < 4; ++r) v[r] = (v[r] >= 0.f) ? v[r] : 0.2f * v[r];
  }
  if (OUT_BF16) {
    constexpr int OPW = OUT_H + 2;
    unsigned short pk[4];
#pragma unroll
    for (int r = 0; r < 4; ++r) pk[r] = f2bf(v[r]);
    *reinterpret_cast<uint2*>(
        obf + (((size_t)b * OPW + oh + 1) * OPW + (ow + 1)) * 64 + wave * 16 + quad * 4) =
        *reinterpret_cast<uint2*>(pk);
  } else {
    *reinterpret_cast<float4*>(
        of32 + ((size_t)b * OUT_H * OUT_H + o) * 64 + wave * 16 + quad * 4) =
        *reinterpret_cast<float4*>(v);
  }
}

// ---------------- bilinear 8->64 upsample + sigmoid gate -> am_cl bf16 [b][4096][64] ----------------
__global__ void __launch_bounds__(256) upsample_gate_k(
    const float* __restrict__ y3cl, const float* __restrict__ x,
    unsigned short* __restrict__ am_cl)
{
  const int b = blockIdx.x >> 6, oh = blockIdx.x & 63;
  const int t = threadIdx.x;
  __shared__ float s0[512], s1[512];
  float sh = (oh + 0.5f) * 0.125f - 0.5f;
  float fh = floorf(sh); float ah = sh - fh; int h0 = (int)fh;
  int h0c = min(7, max(0, h0)), h1c = min(7, max(0, h0 + 1));
  const float* yb = y3cl + (size_t)b * 4096;
  for (int i = t; i < 512; i += 256) { s0[i] = yb[h0c * 512 + i]; s1[i] = yb[h1c * 512 + i]; }
  __syncthreads();
  const int ow = t >> 2, cq = t & 3;
  float sw = (ow + 0.5f) * 0.125f - 0.5f;
  float fw = floorf(sw); float aw = sw - fw; int w0 = (int)fw;
  int w0c = min(7, max(0, w0)), w1c = min(7, max(0, w0 + 1));
  const int n = oh * 64 + ow;
  const float* xb = x + (size_t)b * 64 * 4096 + n;
  unsigned short* ap = am_cl + ((size_t)b * 4096 + n) * 64 + cq * 16;
#pragma unroll
  for (int u = 0; u < 4; ++u) {
    int c0 = cq * 16 + u * 4;
    float4 a00 = *reinterpret_cast<const float4*>(&s0[w0c * 64 + c0]);
    float4 a01 = *reinterpret_cast<const float4*>(&s0[w1c * 64 + c0]);
    float4 a10 = *reinterpret_cast<const float4*>(&s1[w0c * 64 + c0]);
    float4 a11 = *reinterpret_cast<const float4*>(&s1[w1c * 64 + c0]);
    float i0[4] = {a00.x * (1.f - aw) + a01.x * aw, a00.y * (1.f - aw) + a01.y * aw,
                   a00.z * (1.f - aw) + a01.z * aw, a00.w * (1.f - aw) + a01.w * aw};
    float i1[4] = {a10.x * (1.f - aw) + a11.x * aw, a10.y * (1.f - aw) + a11.y * aw,
                   a10.z * (1.f - aw) + a11.z * aw, a10.w * (1.f - aw) + a11.w * aw};
    unsigned short pk[4];
#pragma unroll
    for (int vi = 0; vi < 4; ++vi) {
      float vv = i0[vi] * (1.f - ah) + i1[vi] * ah;
      float xv = xb[(size_t)(c0 + vi) * 4096];
      float sig = 1.f / (1.f + __expf(-vv));
      pk[vi] = f2bf(sig * xv);
    }
    *reinterpret_cast<uint2*>(ap + u * 4) = *reinterpret_cast<uint2*>(pk);
  }
}

// ---------------- proj MFMA: [96 x 64] @ am_cl -> thph bf16 [b][n][64], g16 bf16 [b][32][n] ----------------
__global__ void __launch_bounds__(256) projmf_k(
    const unsigned short* __restrict__ am_cl, const unsigned short* __restrict__ wproj,
    const float* __restrict__ bproj, unsigned short* __restrict__ thph,
    unsigned short* __restrict__ g16)
{
  const int t = threadIdx.x, wave = t >> 6, lane = t & 63;
  const int n15 = lane & 15, quad = lane >> 4;
  const int b = blockIdx.x >> 6;
  const int ntile = (blockIdx.x & 63) * 4 + wave;
  const int n = ntile * 16 + n15;
  const unsigned short* ab = am_cl + ((size_t)b * N_ + n) * 64;
  const short8 bf0 = *reinterpret_cast<const short8*>(ab + quad * 8);
  const short8 bf1 = *reinterpret_cast<const short8*>(ab + 32 + quad * 8);
#pragma unroll
  for (int mt = 0; mt < 6; ++mt) {
    short8 a0 = *reinterpret_cast<const short8*>(wproj + ((size_t)mt * 16 + n15) * 64 + quad * 8);
    short8 a1 = *reinterpret_cast<const short8*>(wproj + ((size_t)mt * 16 + n15) * 64 + 32 + quad * 8);
    floatx4 acc = {0.f, 0.f, 0.f, 0.f};
    acc = __builtin_amdgcn_mfma_f32_16x16x32_bf16(a0, bf0, acc, 0, 0, 0);
    acc = __builtin_amdgcn_mfma_f32_16x16x32_bf16(a1, bf1, acc, 0, 0, 0);
    const float4 bv = *reinterpret_cast<const float4*>(bproj + mt * 16 + quad * 4);
    float v[4] = {acc[0] + bv.x, acc[1] + bv.y, acc[2] + bv.z, acc[3] + bv.w};
    if (mt < 4) {
      unsigned short pk[4];
#pragma unroll
      for (int r = 0; r < 4; ++r) pk[r] = f2bf(v[r]);
      *reinterpret_cast<uint2*>(thph + ((size_t)b * N_ + n) * 64 + mt * 16 + quad * 4) =
          *reinterpret_cast<uint2*>(pk);
    } else {
#pragma unroll
      for (int r = 0; r < 4; ++r)
        g16[((size_t)b * 32 + (mt - 4) * 16 + quad * 4 + r) * N_ + n] = f2bf(v[r]);
    }
  }
}

// ---------------- pass A: l_j = sum_i exp2(S'_ij), partial over i-quarter ----------------
__global__ void __launch_bounds__(256) attn_stats_k(
    const unsigned short* __restrict__ thph, float* __restrict__ lpart)
{
  const int b  = blockIdx.y;
  const int iz = blockIdx.z;
  const int j0 = blockIdx.x * 128;
  const int t = threadIdx.x, wave = t >> 6, lane = t & 63;
  const int n15 = lane & 15, quad = lane >> 4;
  const int jw = j0 + wave * 32;
  const unsigned short* base = thph + (size_t)b * N_ * 64;
  const short8 b0 = *reinterpret_cast<const short8*>(base + (size_t)(jw + n15) * 64 + 32 + quad * 8);
  const short8 b1 = *reinterpret_cast<const short8*>(base + (size_t)(jw + 16 + n15) * 64 + 32 + quad * 8);
  float ls0 = 0.f, ls1 = 0.f;
  const unsigned short* ab = base + (size_t)(iz * 1024 + n15) * 64 + quad * 8;
#pragma unroll 4
  for (int ii = 0; ii < 64; ++ii) {
    short8 a = *reinterpret_cast<const short8*>(ab + (size_t)ii * 1024);
    floatx4 z0 = {0.f, 0.f, 0.f, 0.f}, z1 = {0.f, 0.f, 0.f, 0.f};
    z0 = __builtin_amdgcn_mfma_f32_16x16x32_bf16(a, b0, z0, 0, 0, 0);
    z1 = __builtin_amdgcn_mfma_f32_16x16x32_bf16(a, b1, z1, 0, 0, 0);
    ls0 += exp2f(z0[0]) + exp2f(z0[1]) + exp2f(z0[2]) + exp2f(z0[3]);
    ls1 += exp2f(z1[0]) + exp2f(z1[1]) + exp2f(z1[2]) + exp2f(z1[3]);
  }
  ls0 += __shfl_xor(ls0, 16); ls0 += __shfl_xor(ls0, 32);
  ls1 += __shfl_xor(ls1, 16); ls1 += __shfl_xor(ls1, 32);
  if (quad == 0) {
    lpart[((size_t)iz * B_ + b) * N_ + jw + n15]      = ls0;
    lpart[((size_t)iz * B_ + b) * N_ + jw + 16 + n15] = ls1;
  }
}

// ---------------- pass B: Y[i][c] = sum_j exp2(S')/l_j * g[c][j] ----------------
__global__ void __launch_bounds__(256) attn_pv_k(
    const unsigned short* __restrict__ thph, const unsigned short* __restrict__ g16,
    const float* __restrict__ lpart, float* __restrict__ y2p)
{
  const int b  = blockIdx.y;
  const int i0 = blockIdx.x * 64;
  const int jh = blockIdx.z;
  const int t = threadIdx.x, wave = t >> 6, lane = t & 63;
  const int n15 = lane & 15, quad = lane >> 4;
  const int iw = i0 + wave * 16;
  const unsigned short* base  = thph + (size_t)b * N_ * 64;
  const unsigned short* gbase = g16  + (size_t)b * 32 * N_;
  __shared__ float s_P[4][16][68];
  const short8 afrag = *reinterpret_cast<const short8*>(base + (size_t)(iw + n15) * 64 + quad * 8);
  floatx4 Y0 = {0.f, 0.f, 0.f, 0.f}, Y1 = {0.f, 0.f, 0.f, 0.f};
  for (int j0 = jh * 2048; j0 < jh * 2048 + 2048; j0 += 64) {
    float lv = lpart[(size_t)b * N_ + j0 + lane]
             + lpart[((size_t)1 * B_ + b) * N_ + j0 + lane]
             + lpart[((size_t)2 * B_ + b) * N_ + j0 + lane]
             + lpart[((size_t)3 * B_ + b) * N_ + j0 + lane];
    float rlv = 1.f / lv;
#pragma unroll
    for (int js = 0; js < 4; ++js) {
      short8 bfr = *reinterpret_cast<const short8*>(
          base + (size_t)(j0 + js * 16 + n15) * 64 + 32 + quad * 8);
      floatx4 z = {0.f, 0.f, 0.f, 0.f};
      z = __builtin_amdgcn_mfma_f32_16x16x32_bf16(afrag, bfr, z, 0, 0, 0);
      float r = __shfl(rlv, js * 16 + n15, 64);
#pragma unroll
      for (int reg = 0; reg < 4; ++reg)
        s_P[wave][quad * 4 + reg][js * 16 + n15] = exp2f(z[reg]) * r;
    }
#pragma unroll
    for (int kc = 0; kc < 2; ++kc) {
      const float* pp = &s_P[wave][n15][kc * 32 + quad * 8];
      short8 pa;
#pragma unroll
      for (int e = 0; e < 8; ++e) pa[e] = (short)f2bf(pp[e]);
      short8 bg0 = *reinterpret_cast<const short8*>(
          gbase + (size_t)n15 * N_ + j0 + kc * 32 + quad * 8);
      short8 bg1 = *reinterpret_cast<const short8*>(
          gbase + (size_t)(16 + n15) * N_ + j0 + kc * 32 + quad * 8);
      Y0 = __builtin_amdgcn_mfma_f32_16x16x32_bf16(pa, bg0, Y0, 0, 0, 0);
      Y1 = __builtin_amdgcn_mfma_f32_16x16x32_bf16(pa, bg1, Y1, 0, 0, 0);
    }
  }
#pragma unroll
  for (int reg = 0; reg < 4; ++reg) {
    y2p[(((size_t)jh * B_ + b) * 32 + n15)      * N_ + iw + quad * 4 + reg] = Y0[reg];
    y2p[(((size_t)jh * B_ + b) * 32 + 16 + n15) * N_ + iw + quad * 4 + reg] = Y1[reg];
  }
}

// ---------------- final: out = (W_y(y2) + am) * x ----------------
__global__ void __launch_bounds__(256) final_k(
    const float* __restrict__ y2p, const float* __restrict__ w_w,
    const float* __restrict__ w_b, const unsigned short* __restrict__ am_cl,
    const float* __restrict__ x, float* __restrict__ out)
{
  const int n  = blockIdx.x * 256 + threadIdx.x;
  const int o0 = blockIdx.y * 8;
  const int b  = blockIdx.z;
  float acc[8];
#pragma unroll
  for (int u = 0; u < 8; ++u) acc[u] = w_b[o0 + u];
  const float* yp0 = y2p + (size_t)b * 32 * N_ + n;
  const float* yp1 = y2p + ((size_t)B_ + b) * 32 * N_ + n;
  for (int c = 0; c < 32; ++c) {
    float v = yp0[(size_t)c * N_] + yp1[(size_t)c * N_];
#pragma unroll
    for (int u = 0; u < 8; ++u) acc[u] += w_w[(o0 + u) * 32 + c] * v;
  }
  const short8 amv = *reinterpret_cast<const short8*>(am_cl + ((size_t)b * N_ + n) * 64 + o0);
#pragma unroll
  for (int u = 0; u < 8; ++u) {
    size_t off = ((size_t)b * 64 + o0 + u) * N_ + n;
    out[off] = (acc[u] + bf2f((unsigned short)amv[u])) * x[off];
  }
}

extern "C" void kernel_launch(void* const* d_in, const int* in_sizes, int n_in,
                              void* d_out, int out_size, void* d_ws, size_t ws_size,
                              hipStream_t stream) {
  const float* x    = (const float*)d_in[0];
  const float* d1_w = (const float*)d_in[1];
  const float* d1_b = (const float*)d_in[2];
  const float* d2_w = (const float*)d_in[3];
  const float* d2_b = (const float*)d_in[4];
  const float* d3_w = (const float*)d_in[5];
  const float* d3_b = (const float*)d_in[6];
  const float* g_w  = (const float*)d_in[7];
  const float* g_b  = (const float*)d_in[8];
  const float* th_w = (const float*)d_in[9];
  const float* th_b = (const float*)d_in[10];
  const float* ph_w = (const float*)d_in[11];
  const float* ph_b = (const float*)d_in[12];
  const float* w_w  = (const float*)d_in[13];
  const float* w_b  = (const float*)d_in[14];
  float* out = (float*)d_out;

  // workspace carve (bytes, all regions 256B-aligned)
  char* p = (char*)d_ws;
  unsigned short* am_cl = (unsigned short*)p;            p += (size_t)B_ * N_ * 64 * 2;   // 2 MB
  unsigned short* thph  = (unsigned short*)p;            p += (size_t)B_ * N_ * 64 * 2;   // 2 MB
  unsigned short* g16   = (unsigned short*)p;            p += (size_t)B_ * 32 * N_ * 2;   // 1 MB
  float* lpart          = (float*)p;                     p += (size_t)4 * B_ * N_ * 4;    // 256 KB
  float* y2p            = (float*)p;                     p += (size_t)2 * B_ * 32 * N_ * 4; // 4 MB
  unsigned short* xclp  = (unsigned short*)p;            p += (size_t)B_ * 66 * 66 * 64 * 2;
  unsigned short* y1clp = (unsigned short*)p;            p += (size_t)B_ * 34 * 34 * 64 * 2;
  unsigned short* y2clp = (unsigned short*)p;            p += (size_t)B_ * 18 * 18 * 64 * 2;
  float* y3cl           = (float*)p;                     p += (size_t)B_ * 64 * 64 * 4;   // 64 KB
  unsigned short* wpk   = (unsigned short*)p;            p += (size_t)3 * 36864 * 2;
  unsigned short* wproj = (unsigned short*)p;            p += (size_t)96 * 64 * 2;
  float* bproj          = (float*)p;                     p += (size_t)96 * 4;

  // zero padded borders (interiors are fully overwritten)
  hipMemsetAsync(xclp,  0, (size_t)B_ * 66 * 66 * 64 * 2, stream);
  hipMemsetAsync(y1clp, 0, (size_t)B_ * 34 * 34 * 64 * 2, stream);
  hipMemsetAsync(y2clp, 0, (size_t)B_ * 18 * 18 * 64 * 2, stream);

  pack_w_k<<<64, 256, 0, stream>>>(d1_w, d2_w, d3_w, th_w, ph_w, g_w,
                                   th_b, ph_b, g_b, wpk, wproj, bproj);
  pack_x_k<<<256, 256, 0, stream>>>(x, xclp);
  convmf_k<66, 32, true,  true ><<<256, 256, 0, stream>>>(xclp,  wpk,             d1_b, y1clp, nullptr);
  convmf_k<34, 16, true,  true ><<<64,  256, 0, stream>>>(y1clp, wpk + 36864,     d2_b, y2clp, nullptr);
  convmf_k<18,  8, false, false><<<16,  256, 0, stream>>>(y2clp, wpk + 2 * 36864, d3_b, nullptr, y3cl);
  upsample_gate_k<<<256, 256, 0, stream>>>(y3cl, x, am_cl);
  projmf_k<<<256, 256, 0, stream>>>(am_cl, wproj, bproj, thph, g16);
  attn_stats_k<<<dim3(32, 4, 4), 256, 0, stream>>>(thph, lpart);
  attn_pv_k<<<dim3(64, 4, 2), 256, 0, stream>>>(thph, g16, lpart, y2p);
  final_k<<<dim3(16, 8, 4), 256, 0, stream>>>(y2p, w_w, w_b, am_cl, x, out);
}

// Round 4
// 212.514 us; speedup vs baseline: 2.4235x; 1.0308x over previous
//
#include <hip/hip_runtime.h>

#define B_ 4
#define C_ 64
#define IC_ 32
#define N_ 4096
#define LOG2E 1.44269504088896341f

typedef __attribute__((ext_vector_type(8))) short short8;
typedef __attribute__((ext_vector_type(4))) float floatx4;

__device__ __forceinline__ unsigned short f2bf(float f) {
  unsigned u = __float_as_uint(f);
  u += 0x7FFFu + ((u >> 16) & 1u);   // round-to-nearest-even
  return (unsigned short)(u >> 16);
}
__device__ __forceinline__ float bf2f(unsigned short h) {
  return __uint_as_float(((unsigned)h) << 16);
}

// ---------------- weight pack: convs -> [tap][oc][ic] bf16; proj -> [96][64] bf16 ----------------
__global__ void __launch_bounds__(256) pack_w_k(
    const float* __restrict__ d1_w, const float* __restrict__ d2_w, const float* __restrict__ d3_w,
    const float* __restrict__ th_w, const float* __restrict__ ph_w, const float* __restrict__ g_w,
    const float* __restrict__ th_b, const float* __restrict__ ph_b, const float* __restrict__ g_b,
    unsigned short* __restrict__ wpk, unsigned short* __restrict__ wproj, float* __restrict__ bproj)
{
  const int tid = blockIdx.x * 256 + threadIdx.x;
  for (int idx = tid; idx < 3 * 36864; idx += gridDim.x * 256) {
    int cv = idx / 36864, r = idx % 36864;
    int tap = r / 4096, r2 = r % 4096;
    int oc = r2 >> 6, ic = r2 & 63;
    const float* src = (cv == 0) ? d1_w : (cv == 1) ? d2_w : d3_w;
    wpk[(size_t)cv * 36864 + tap * 4096 + oc * 64 + ic] = f2bf(src[oc * 576 + ic * 9 + tap]);
  }
  for (int idx = tid; idx < 6144; idx += gridDim.x * 256) {
    int m = idx >> 6, ic = idx & 63;
    float v = (m < 32) ? LOG2E * th_w[m * 64 + ic]
            : (m < 64) ? ph_w[(m - 32) * 64 + ic]
                       : g_w[(m - 64) * 64 + ic];
    wproj[m * 64 + ic] = f2bf(v);
  }
  for (int m = tid; m < 96; m += gridDim.x * 256) {
    bproj[m] = (m < 32) ? LOG2E * th_b[m] : (m < 64) ? ph_b[m - 32] : g_b[m - 64];
  }
}

// ---------------- pack x: [b][64c][64h][64w] f32 -> padded channel-last bf16 [b][66][66][64] ----------------
__global__ void __launch_bounds__(256) pack_x_k(
    const float* __restrict__ x, unsigned short* __restrict__ xclp)
{
  const int b = blockIdx.x >> 6, h = blockIdx.x & 63;
  const int t = threadIdx.x;
  __shared__ float s[64][65];
  for (int idx = t; idx < 4096; idx += 256) {
    int c = idx >> 6, w = idx & 63;
    s[c][w] = x[((size_t)(b * 64 + c)) * 4096 + h * 64 + w];
  }
  __syncthreads();
  for (int idx = t; idx < 4096; idx += 256) {
    int w = idx >> 6, c = idx & 63;
    xclp[(((size_t)b * 66 + h + 1) * 66 + (w + 1)) * 64 + c] = f2bf(s[c][w]);
  }
}

// ---------------- implicit-GEMM conv 3x3 s2, 64->64 ch, MFMA bf16, 1 wave/block ------
template<int IN_PW, int OUT_H, bool LRELU, bool OUT_BF16>
__global__ void __launch_bounds__(64) convmf_k(
    const unsigned short* __restrict__ xin, const unsigned short* __restrict__ wp,
    const float* __restrict__ bias, unsigned short* __restrict__ obf,
    float* __restrict__ of32)
{
  constexpr int NTILES = OUT_H * OUT_H / 16;
  const int lane = threadIdx.x;
  const int n15 = lane & 15, quad = lane >> 4;
  int bx = blockIdx.x;
  const int octile = bx & 3; bx >>= 2;
  const int otile = bx % NTILES;
  const int b = bx / NTILES;
  const int o = otile * 16 + n15;
  const int oh = o / OUT_H, ow = o % OUT_H;
  const unsigned short* xb = xin + (size_t)b * IN_PW * IN_PW * 64;
  floatx4 acc = {0.f, 0.f, 0.f, 0.f};
#pragma unroll
  for (int tap = 0; tap < 9; ++tap) {
    const int kh = tap / 3, kw = tap % 3;
    const unsigned short* xpix = xb + ((size_t)(oh * 2 + kh) * IN_PW + (ow * 2 + kw)) * 64;
#pragma unroll
    for (int ks = 0; ks < 2; ++ks) {
      short8 af = *reinterpret_cast<const short8*>(
          wp + ((size_t)tap * 64 + octile * 16 + n15) * 64 + ks * 32 + quad * 8);
      short8 bf = *reinterpret_cast<const short8*>(xpix + ks * 32 + quad * 8);
      acc = __builtin_amdgcn_mfma_f32_16x16x32_bf16(af, bf, acc, 0, 0, 0);
    }
  }
  const float4 bv = *reinterpret_cast<const float4*>(bias + octile * 16 + quad * 4);
  float v[4] = {acc[0] + bv.x, acc[1] + bv.y, acc[2] + bv.z, acc[3] + bv.w};
  if (LRELU) {
#pragma unroll
    for (int r = 0; r < 4; ++r) v[r] = (v[r] >= 0.f) ? v[r] : 0.2f * v[r];
  }
  if (OUT_BF16) {
    constexpr int OPW = OUT_H + 2;
    unsigned short pk[4];
#pragma unroll
    for (int r = 0; r < 4; ++r) pk[r] = f2bf(v[r]);
    *reinterpret_cast<uint2*>(
        obf + (((size_t)b * OPW + oh + 1) * OPW + (ow + 1)) * 64 + octile * 16 + quad * 4) =
        *reinterpret_cast<uint2*>(pk);
  } else {
    *reinterpret_cast<float4*>(
        of32 + ((size_t)b * OUT_H * OUT_H + o) * 64 + octile * 16 + quad * 4) =
        *reinterpret_cast<float4*>(v);
  }
}

// ---------------- bilinear 8->64 upsample + sigmoid gate -> am_cl bf16 [b][4096][64] ----------------
__global__ void __launch_bounds__(256) upsample_gate_k(
    const float* __restrict__ y3cl, const float* __restrict__ x,
    unsigned short* __restrict__ am_cl)
{
  const int b = blockIdx.x >> 6, oh = blockIdx.x & 63;
  const int t = threadIdx.x;
  __shared__ float s0[512], s1[512];
  float sh = (oh + 0.5f) * 0.125f - 0.5f;
  float fh = floorf(sh); float ah = sh - fh; int h0 = (int)fh;
  int h0c = min(7, max(0, h0)), h1c = min(7, max(0, h0 + 1));
  const float* yb = y3cl + (size_t)b * 4096;
  for (int i = t; i < 512; i += 256) { s0[i] = yb[h0c * 512 + i]; s1[i] = yb[h1c * 512 + i]; }
  __syncthreads();
  const int ow = t >> 2, cq = t & 3;
  float sw = (ow + 0.5f) * 0.125f - 0.5f;
  float fw = floorf(sw); float aw = sw - fw; int w0 = (int)fw;
  int w0c = min(7, max(0, w0)), w1c = min(7, max(0, w0 + 1));
  const int n = oh * 64 + ow;
  const float* xb = x + (size_t)b * 64 * 4096 + n;
  unsigned short* ap = am_cl + ((size_t)b * 4096 + n) * 64 + cq * 16;
#pragma unroll
  for (int u = 0; u < 4; ++u) {
    int c0 = cq * 16 + u * 4;
    float4 a00 = *reinterpret_cast<const float4*>(&s0[w0c * 64 + c0]);
    float4 a01 = *reinterpret_cast<const float4*>(&s0[w1c * 64 + c0]);
    float4 a10 = *reinterpret_cast<const float4*>(&s1[w0c * 64 + c0]);
    float4 a11 = *reinterpret_cast<const float4*>(&s1[w1c * 64 + c0]);
    float i0[4] = {a00.x * (1.f - aw) + a01.x * aw, a00.y * (1.f - aw) + a01.y * aw,
                   a00.z * (1.f - aw) + a01.z * aw, a00.w * (1.f - aw) + a01.w * aw};
    float i1[4] = {a10.x * (1.f - aw) + a11.x * aw, a10.y * (1.f - aw) + a11.y * aw,
                   a10.z * (1.f - aw) + a11.z * aw, a10.w * (1.f - aw) + a11.w * aw};
    unsigned short pk[4];
#pragma unroll
    for (int vi = 0; vi < 4; ++vi) {
      float vv = i0[vi] * (1.f - ah) + i1[vi] * ah;
      float xv = xb[(size_t)(c0 + vi) * 4096];
      float sig = 1.f / (1.f + __expf(-vv));
      pk[vi] = f2bf(sig * xv);
    }
    *reinterpret_cast<uint2*>(ap + u * 4) = *reinterpret_cast<uint2*>(pk);
  }
}

// ---------------- proj MFMA: [96 x 64] @ am_cl -> thph bf16 [b][n][64], g16 bf16 [b][32][n] ----------------
__global__ void __launch_bounds__(256) projmf_k(
    const unsigned short* __restrict__ am_cl, const unsigned short* __restrict__ wproj,
    const float* __restrict__ bproj, unsigned short* __restrict__ thph,
    unsigned short* __restrict__ g16)
{
  const int t = threadIdx.x, wave = t >> 6, lane = t & 63;
  const int n15 = lane & 15, quad = lane >> 4;
  const int b = blockIdx.x >> 6;
  const int ntile = (blockIdx.x & 63) * 4 + wave;
  const int n = ntile * 16 + n15;
  const unsigned short* ab = am_cl + ((size_t)b * N_ + n) * 64;
  const short8 bf0 = *reinterpret_cast<const short8*>(ab + quad * 8);
  const short8 bf1 = *reinterpret_cast<const short8*>(ab + 32 + quad * 8);
#pragma unroll
  for (int mt = 0; mt < 6; ++mt) {
    short8 a0 = *reinterpret_cast<const short8*>(wproj + ((size_t)mt * 16 + n15) * 64 + quad * 8);
    short8 a1 = *reinterpret_cast<const short8*>(wproj + ((size_t)mt * 16 + n15) * 64 + 32 + quad * 8);
    floatx4 acc = {0.f, 0.f, 0.f, 0.f};
    acc = __builtin_amdgcn_mfma_f32_16x16x32_bf16(a0, bf0, acc, 0, 0, 0);
    acc = __builtin_amdgcn_mfma_f32_16x16x32_bf16(a1, bf1, acc, 0, 0, 0);
    const float4 bv = *reinterpret_cast<const float4*>(bproj + mt * 16 + quad * 4);
    float v[4] = {acc[0] + bv.x, acc[1] + bv.y, acc[2] + bv.z, acc[3] + bv.w};
    if (mt < 4) {
      unsigned short pk[4];
#pragma unroll
      for (int r = 0; r < 4; ++r) pk[r] = f2bf(v[r]);
      *reinterpret_cast<uint2*>(thph + ((size_t)b * N_ + n) * 64 + mt * 16 + quad * 4) =
          *reinterpret_cast<uint2*>(pk);
    } else {
#pragma unroll
      for (int r = 0; r < 4; ++r)
        g16[((size_t)b * 32 + (mt - 4) * 16 + quad * 4 + r) * N_ + n] = f2bf(v[r]);
    }
  }
}

// ---------------- pass A: l_j = sum_i exp2(S'_ij), partial over i-eighth ----------------
// grid (32, B, 8); wave owns 32 j-columns, loops its 512-i slice.
__global__ void __launch_bounds__(256) attn_stats_k(
    const unsigned short* __restrict__ thph, float* __restrict__ lpart)
{
  const int b  = blockIdx.y;
  const int iz = blockIdx.z;
  const int j0 = blockIdx.x * 128;
  const int t = threadIdx.x, wave = t >> 6, lane = t & 63;
  const int n15 = lane & 15, quad = lane >> 4;
  const int jw = j0 + wave * 32;
  const unsigned short* base = thph + (size_t)b * N_ * 64;
  const short8 b0 = *reinterpret_cast<const short8*>(base + (size_t)(jw + n15) * 64 + 32 + quad * 8);
  const short8 b1 = *reinterpret_cast<const short8*>(base + (size_t)(jw + 16 + n15) * 64 + 32 + quad * 8);
  float ls0 = 0.f, ls1 = 0.f;
  const unsigned short* ab = base + (size_t)(iz * 512 + n15) * 64 + quad * 8;
#pragma unroll 4
  for (int ii = 0; ii < 32; ++ii) {
    short8 a = *reinterpret_cast<const short8*>(ab + (size_t)ii * 1024);
    floatx4 z0 = {0.f, 0.f, 0.f, 0.f}, z1 = {0.f, 0.f, 0.f, 0.f};
    z0 = __builtin_amdgcn_mfma_f32_16x16x32_bf16(a, b0, z0, 0, 0, 0);
    z1 = __builtin_amdgcn_mfma_f32_16x16x32_bf16(a, b1, z1, 0, 0, 0);
    ls0 += exp2f(z0[0]) + exp2f(z0[1]) + exp2f(z0[2]) + exp2f(z0[3]);
    ls1 += exp2f(z1[0]) + exp2f(z1[1]) + exp2f(z1[2]) + exp2f(z1[3]);
  }
  ls0 += __shfl_xor(ls0, 16); ls0 += __shfl_xor(ls0, 32);
  ls1 += __shfl_xor(ls1, 16); ls1 += __shfl_xor(ls1, 32);
  if (quad == 0) {
    lpart[((size_t)iz * B_ + b) * N_ + jw + n15]      = ls0;
    lpart[((size_t)iz * B_ + b) * N_ + jw + 16 + n15] = ls1;
  }
}

// ---------------- fold softmax denom into g: g[c][j] *= 1/l_j (in place) ----------------
__global__ void __launch_bounds__(256) scale_g_k(
    const float* __restrict__ lpart, unsigned short* __restrict__ g16)
{
  const int b = blockIdx.y;
  const int j = blockIdx.x * 256 + threadIdx.x;
  float l = 0.f;
#pragma unroll
  for (int iz = 0; iz < 8; ++iz) l += lpart[((size_t)iz * B_ + b) * N_ + j];
  const float rl = 1.f / l;
  unsigned short* gp = g16 + (size_t)b * 32 * N_ + j;
#pragma unroll
  for (int c = 0; c < 32; ++c) {
    gp[(size_t)c * N_] = f2bf(bf2f(gp[(size_t)c * N_]) * rl);
  }
}

// ---------------- pass B: Y[i][c] = sum_j exp2(S') * gs[c][j];  gs pre-scaled --------
// S^T trick: A=phi, B=theta -> P frag has i=lane&15; j permuted via ds_bpermute.
// grid (64, B, 4); wave owns 16 i-rows, loops its j-quarter in 64-j chunks. No LDS.
__global__ void __launch_bounds__(256) attn_pv_k(
    const unsigned short* __restrict__ thph, const unsigned short* __restrict__ g16,
    unsigned short* __restrict__ y2p)
{
  const int b  = blockIdx.y;
  const int jh = blockIdx.z;
  const int t = threadIdx.x, wave = t >> 6, lane = t & 63;
  const int n15 = lane & 15, quad = lane >> 4;
  const int iw = blockIdx.x * 64 + wave * 16;
  const unsigned short* base  = thph + (size_t)b * N_ * 64;
  const unsigned short* gs    = g16  + (size_t)b * 32 * N_;
  // theta as B-operand: B[n=i=n15][k=quad*8+e] (theta = ch 0..31, log2e pre-folded)
  const short8 bth = *reinterpret_cast<const short8*>(base + (size_t)(iw + n15) * 64 + quad * 8);
  const bool bsel = (quad >> 1) & 1;
  const int addr0 = (n15 + ((quad & 1) << 5)) << 2;   // source lane q_s0=2*(quad&1)
  const int addr1 = addr0 + 64;                       // q_s0 + 1
  floatx4 Y0 = {0.f, 0.f, 0.f, 0.f}, Y1 = {0.f, 0.f, 0.f, 0.f};
  for (int j0 = jh * 1024; j0 < jh * 1024 + 1024; j0 += 64) {
    unsigned pk[4][2];
#pragma unroll
    for (int js = 0; js < 4; ++js) {
      // phi as A-operand: A[m=j=j0+js*16+n15][k] -> D[m=j_loc=quad*4+r][n=i=n15]
      short8 aph = *reinterpret_cast<const short8*>(
          base + (size_t)(j0 + js * 16 + n15) * 64 + 32 + quad * 8);
      floatx4 z = {0.f, 0.f, 0.f, 0.f};
      z = __builtin_amdgcn_mfma_f32_16x16x32_bf16(aph, bth, z, 0, 0, 0);
      float e0 = exp2f(z[0]), e1 = exp2f(z[1]), e2 = exp2f(z[2]), e3 = exp2f(z[3]);
      // pack (truncate to bf16): lo16 = e_even, hi16 = e_odd
      pk[js][0] = __builtin_amdgcn_perm(__float_as_uint(e1), __float_as_uint(e0), 0x07060302);
      pk[js][1] = __builtin_amdgcn_perm(__float_as_uint(e3), __float_as_uint(e2), 0x07060302);
    }
#pragma unroll
    for (int kc = 0; kc < 2; ++kc) {
      // target lane (q_t,n15) A-frag k=q_t*8+e needs source js = kc*2 + (q_t>>1),
      // words from source lanes n15+16*(2*(q_t&1)) and +16.
      unsigned a00 = __builtin_amdgcn_ds_bpermute(addr0, (int)pk[kc * 2][0]);
      unsigned b00 = __builtin_amdgcn_ds_bpermute(addr0, (int)pk[kc * 2 + 1][0]);
      unsigned a01 = __builtin_amdgcn_ds_bpermute(addr0, (int)pk[kc * 2][1]);
      unsigned b01 = __builtin_amdgcn_ds_bpermute(addr0, (int)pk[kc * 2 + 1][1]);
      unsigned a10 = __builtin_amdgcn_ds_bpermute(addr1, (int)pk[kc * 2][0]);
      unsigned b10 = __builtin_amdgcn_ds_bpermute(addr1, (int)pk[kc * 2 + 1][0]);
      unsigned a11 = __builtin_amdgcn_ds_bpermute(addr1, (int)pk[kc * 2][1]);
      unsigned b11 = __builtin_amdgcn_ds_bpermute(addr1, (int)pk[kc * 2 + 1][1]);
      union { unsigned u[4]; short8 s; } fa;
      fa.u[0] = bsel ? b00 : a00;
      fa.u[1] = bsel ? b01 : a01;
      fa.u[2] = bsel ? b10 : a10;
      fa.u[3] = bsel ? b11 : a11;
      short8 bg0 = *reinterpret_cast<const short8*>(
          gs + (size_t)n15 * N_ + j0 + kc * 32 + quad * 8);
      short8 bg1 = *reinterpret_cast<const short8*>(
          gs + (size_t)(16 + n15) * N_ + j0 + kc * 32 + quad * 8);
      Y0 = __builtin_amdgcn_mfma_f32_16x16x32_bf16(fa.s, bg0, Y0, 0, 0, 0);
      Y1 = __builtin_amdgcn_mfma_f32_16x16x32_bf16(fa.s, bg1, Y1, 0, 0, 0);
    }
  }
  // D: lane (q,n15): Y[i=iw+q*4+r][c=n15 (+16)] -> pack 4 bf16, one 8B store each
  unsigned w0[2], w1[2];
  w0[0] = ((unsigned)f2bf(Y0[1]) << 16) | f2bf(Y0[0]);
  w0[1] = ((unsigned)f2bf(Y0[3]) << 16) | f2bf(Y0[2]);
  w1[0] = ((unsigned)f2bf(Y1[1]) << 16) | f2bf(Y1[0]);
  w1[1] = ((unsigned)f2bf(Y1[3]) << 16) | f2bf(Y1[2]);
  *reinterpret_cast<uint2*>(
      y2p + (((size_t)jh * B_ + b) * 32 + n15) * N_ + iw + quad * 4) =
      *reinterpret_cast<uint2*>(w0);
  *reinterpret_cast<uint2*>(
      y2p + (((size_t)jh * B_ + b) * 32 + 16 + n15) * N_ + iw + quad * 4) =
      *reinterpret_cast<uint2*>(w1);
}

// ---------------- final: out = (W_y(y2) + am) * x ----------------
__global__ void __launch_bounds__(256) final_k(
    const unsigned short* __restrict__ y2p, const float* __restrict__ w_w,
    const float* __restrict__ w_b, const unsigned short* __restrict__ am_cl,
    const float* __restrict__ x, float* __restrict__ out)
{
  const int n0 = (blockIdx.x * 256 + threadIdx.x) * 2;
  const int o0 = blockIdx.y * 8;
  const int b  = blockIdx.z;
  float a0[8], a1[8];
#pragma unroll
  for (int u = 0; u < 8; ++u) { a0[u] = w_b[o0 + u]; a1[u] = a0[u]; }
  for (int c = 0; c < 32; ++c) {
    float s0 = 0.f, s1 = 0.f;
#pragma unroll
    for (int ph = 0; ph < 4; ++ph) {
      unsigned v = *reinterpret_cast<const unsigned*>(
          y2p + (((size_t)ph * B_ + b) * 32 + c) * N_ + n0);
      s0 += bf2f((unsigned short)(v & 0xffffu));
      s1 += bf2f((unsigned short)(v >> 16));
    }
#pragma unroll
    for (int u = 0; u < 8; ++u) {
      float wv = w_w[(o0 + u) * 32 + c];
      a0[u] += wv * s0; a1[u] += wv * s1;
    }
  }
  const short8 am0 = *reinterpret_cast<const short8*>(am_cl + ((size_t)b * N_ + n0) * 64 + o0);
  const short8 am1 = *reinterpret_cast<const short8*>(am_cl + ((size_t)b * N_ + n0 + 1) * 64 + o0);
#pragma unroll
  for (int u = 0; u < 8; ++u) {
    size_t off = ((size_t)b * 64 + o0 + u) * N_ + n0;
    float2 xv = *reinterpret_cast<const float2*>(x + off);
    float2 ov;
    ov.x = (a0[u] + bf2f((unsigned short)am0[u])) * xv.x;
    ov.y = (a1[u] + bf2f((unsigned short)am1[u])) * xv.y;
    *reinterpret_cast<float2*>(out + off) = ov;
  }
}

extern "C" void kernel_launch(void* const* d_in, const int* in_sizes, int n_in,
                              void* d_out, int out_size, void* d_ws, size_t ws_size,
                              hipStream_t stream) {
  const float* x    = (const float*)d_in[0];
  const float* d1_w = (const float*)d_in[1];
  const float* d1_b = (const float*)d_in[2];
  const float* d2_w = (const float*)d_in[3];
  const float* d2_b = (const float*)d_in[4];
  const float* d3_w = (const float*)d_in[5];
  const float* d3_b = (const float*)d_in[6];
  const float* g_w  = (const float*)d_in[7];
  const float* g_b  = (const float*)d_in[8];
  const float* th_w = (const float*)d_in[9];
  const float* th_b = (const float*)d_in[10];
  const float* ph_w = (const float*)d_in[11];
  const float* ph_b = (const float*)d_in[12];
  const float* w_w  = (const float*)d_in[13];
  const float* w_b  = (const float*)d_in[14];
  float* out = (float*)d_out;

  char* p = (char*)d_ws;
  unsigned short* am_cl = (unsigned short*)p;  p += (size_t)B_ * N_ * 64 * 2;        // 2 MB
  unsigned short* thph  = (unsigned short*)p;  p += (size_t)B_ * N_ * 64 * 2;        // 2 MB
  unsigned short* g16   = (unsigned short*)p;  p += (size_t)B_ * 32 * N_ * 2;        // 1 MB
  float* lpart          = (float*)p;           p += (size_t)8 * B_ * N_ * 4;         // 512 KB
  unsigned short* y2p   = (unsigned short*)p;  p += (size_t)4 * B_ * 32 * N_ * 2;    // 4 MB
  unsigned short* xclp  = (unsigned short*)p;  p += (size_t)B_ * 66 * 66 * 64 * 2;
  unsigned short* y1clp = (unsigned short*)p;  p += (size_t)B_ * 34 * 34 * 64 * 2;
  unsigned short* y2clp = (unsigned short*)p;  p += (size_t)B_ * 18 * 18 * 64 * 2;
  float* y3cl           = (float*)p;           p += (size_t)B_ * 64 * 64 * 4;
  unsigned short* wpk   = (unsigned short*)p;  p += (size_t)3 * 36864 * 2;
  unsigned short* wproj = (unsigned short*)p;  p += (size_t)96 * 64 * 2;
  float* bproj          = (float*)p;           p += (size_t)96 * 4;

  hipMemsetAsync(xclp,  0, (size_t)B_ * 66 * 66 * 64 * 2, stream);
  hipMemsetAsync(y1clp, 0, (size_t)B_ * 34 * 34 * 64 * 2, stream);
  hipMemsetAsync(y2clp, 0, (size_t)B_ * 18 * 18 * 64 * 2, stream);

  pack_w_k<<<64, 256, 0, stream>>>(d1_w, d2_w, d3_w, th_w, ph_w, g_w,
                                   th_b, ph_b, g_b, wpk, wproj, bproj);
  pack_x_k<<<256, 256, 0, stream>>>(x, xclp);
  convmf_k<66, 32, true,  true ><<<1024, 64, 0, stream>>>(xclp,  wpk,             d1_b, y1clp, nullptr);
  convmf_k<34, 16, true,  true ><<<256,  64, 0, stream>>>(y1clp, wpk + 36864,     d2_b, y2clp, nullptr);
  convmf_k<18,  8, false, false><<<64,   64, 0, stream>>>(y2clp, wpk + 2 * 36864, d3_b, nullptr, y3cl);
  upsample_gate_k<<<256, 256, 0, stream>>>(y3cl, x, am_cl);
  projmf_k<<<256, 256, 0, stream>>>(am_cl, wproj, bproj, thph, g16);
  attn_stats_k<<<dim3(32, 4, 8), 256, 0, stream>>>(thph, lpart);
  scale_g_k<<<dim3(16, 4), 256, 0, stream>>>(lpart, g16);
  attn_pv_k<<<dim3(64, 4, 4), 256, 0, stream>>>(thph, g16, y2p);
  final_k<<<dim3(8, 8, 4), 256, 0, stream>>>(y2p, w_w, w_b, am_cl, x, out);
}